// Round 6
// baseline (471.433 us; speedup 1.0000x reference)
//
#include <hip/hip_runtime.h>
#include <math.h>

#define NN      262144
#define WC      128
#define RR      4
#define OUTD    512
#define IFACED  919
#define CD      1431
#define C4      5724
#define VROWS   1559   // CD + WC virtual rows ([h ; xt])
#define PROJ_J  1157   // 512 out + 645 used iface entries
#define CMAX    2048   // candidate cap (E[n]=524 @ thr 2e-3)
#define ZJT     90     // zmv column tiles of 64 (90*64 >= 5724; last=28)
#define ZKCH    195    // virtual rows per wave (8*195=1560 >= 1559)
#define PJT     19     // proj column tiles of 64 (last=5)
#define PKCH    179    // proj rows per wave (8*179=1432 >= 1431)

// ---- ws word offsets. [0 .. WS_ZERO_WORDS) zeroed by k_init pre-launch.
#define OFF_BARS    0        // u32[8] arrival stripes, 128B apart
#define OFF_REL     256      // u32 release epoch (own line)
#define OFF_CCNT    288      // u32 candidate count (own line)
#define WS_ZERO_WORDS 320
#define OFF_Z       320      // f32[5][C4] per-step z (STORED once, never accumulated)
#define OFF_PO      28940    // f32[512] out-proj (stored once)
#define OFF_IFC     29452    // f32[919] iface (stored once)
#define OFF_BSUM    30372    // f32[512*5] per-block softmax sums (blocks 1..)
#define OFF_CAND    32960    // u64[2048] (8B aligned, even word)
#define OFF_SCORES  37056    // f32[5*NN] plain store/reload by SAME thread

__device__ __forceinline__ float sigm(float x) { return 1.f / (1.f + expf(-x)); }
__device__ __forceinline__ float softplusf(float x) { return x > 20.f ? x : log1pf(expf(x)); }

// agent-scope (device-coherent) accessors — land at the coherent point,
// bypass stale per-XCD L2s. Used ONLY for cross-block data.
__device__ __forceinline__ float gldf(const float* p) {
  return __hip_atomic_load(p, __ATOMIC_RELAXED, __HIP_MEMORY_SCOPE_AGENT);
}
__device__ __forceinline__ void gstf(float* p, float v) {
  __hip_atomic_store(p, v, __ATOMIC_RELAXED, __HIP_MEMORY_SCOPE_AGENT);
}
__device__ __forceinline__ unsigned gldu(const unsigned* p) {
  return __hip_atomic_load(p, __ATOMIC_RELAXED, __HIP_MEMORY_SCOPE_AGENT);
}
__device__ __forceinline__ unsigned long long gldu64(const unsigned long long* p) {
  return __hip_atomic_load(p, __ATOMIC_RELAXED, __HIP_MEMORY_SCOPE_AGENT);
}
__device__ __forceinline__ void gstu64(unsigned long long* p, unsigned long long v) {
  __hip_atomic_store(p, v, __ATOMIC_RELAXED, __HIP_MEMORY_SCOPE_AGENT);
}

// ---- init: zero barrier stripes / release / ccnt (plain launch) ----------
__global__ void k_init(float* __restrict__ ws) {
  if (threadIdx.x < WS_ZERO_WORDS) ws[threadIdx.x] = 0.f;
}

// ---- grid barrier (v3, proven): striped RMW arrivals + broadcast release --
__device__ __forceinline__ void gbar(unsigned* bars, unsigned* rel,
                                     unsigned ep, unsigned grid) {
  asm volatile("s_waitcnt vmcnt(0) lgkmcnt(0)" ::: "memory");  // drain stores
  __syncthreads();                                             // whole block drained
  if (threadIdx.x == 0) {
    __hip_atomic_fetch_add(bars + (blockIdx.x & 7) * 32, 1u,
                           __ATOMIC_RELAXED, __HIP_MEMORY_SCOPE_AGENT);
    if (blockIdx.x == 0) {
      for (;;) {
        unsigned s = 0;
        #pragma unroll
        for (int q = 0; q < 8; ++q)
          s += __hip_atomic_load(bars + q * 32, __ATOMIC_RELAXED, __HIP_MEMORY_SCOPE_AGENT);
        if (s >= ep * grid) break;
        __builtin_amdgcn_s_sleep(1);
      }
      __hip_atomic_store(rel, ep, __ATOMIC_RELAXED, __HIP_MEMORY_SCOPE_AGENT);
    } else {
      while (__hip_atomic_load(rel, __ATOMIC_RELAXED, __HIP_MEMORY_SCOPE_AGENT) < ep)
        __builtin_amdgcn_s_sleep(8);
    }
  }
  __syncthreads();
}

__global__ __launch_bounds__(512, 4) void k_fused(
    const float* __restrict__ x,  const float* __restrict__ dk,
    const float* __restrict__ db, const float* __restrict__ lk,
    const float* __restrict__ lr, const float* __restrict__ lb,
    const float* __restrict__ h0, const float* __restrict__ c0,
    const float* __restrict__ rv, const float* __restrict__ Wo,
    const float* __restrict__ Wi, const float* __restrict__ M,
    const float* __restrict__ us, float* __restrict__ out,
    float* __restrict__ ws)
{
  unsigned* bars = (unsigned*)(ws + OFF_BARS);
  unsigned* rel  = (unsigned*)(ws + OFF_REL);
  unsigned* ccnt = (unsigned*)(ws + OFF_CCNT);
  float* po      = ws + OFF_PO;
  float* ifc     = ws + OFF_IFC;
  float* bsum    = ws + OFF_BSUM;
  float* scores  = ws + OFF_SCORES;
  unsigned long long* cand = (unsigned long long*)(ws + OFF_CAND);
  unsigned ep = 0;

  __shared__ float sv[VROWS];       // [h(1431) ; xt(128)] per-block replica
  __shared__ float scc[CD];         // c, per-block replica
  __shared__ float sxw[512];        // dense partials; [0:128) holds xw after
  __shared__ float zred[512];       // cross-wave matvec reduction
  __shared__ float s_rk[RR * WC];
  __shared__ float s_wk[WC];
  __shared__ float swred[8][5];
  __shared__ float ssum[5];
  __shared__ unsigned long long sc[CMAX];
  __shared__ unsigned long long srt[CMAX];
  __shared__ float cpe[200];

  const int wave = threadIdx.x >> 6, lane = threadIdx.x & 63;

  // ---- init: h0/c0 -> LDS; xw = x@dense+bias computed redundantly per block
  for (int t = threadIdx.x; t < CD; t += 512) { sv[t] = h0[t]; scc[t] = c0[t]; }
  {
    int j = threadIdx.x & (WC - 1), kc = threadIdx.x >> 7;   // 4 k-chunks x 128
    const float* col = dk + j;
    float a = 0.f;
    int k0 = kc * 128;
    #pragma unroll 8
    for (int k = k0; k < k0 + 128; ++k) a = fmaf(x[k], col[(size_t)k * WC], a);
    sxw[threadIdx.x] = a;
  }
  __syncthreads();
  {
    float v = 0.f;
    if (threadIdx.x < WC)
      v = db[threadIdx.x] + sxw[threadIdx.x] + sxw[threadIdx.x + 128] +
          sxw[threadIdx.x + 256] + sxw[threadIdx.x + 384];
    __syncthreads();
    if (threadIdx.x < WC) sxw[threadIdx.x] = v;
    __syncthreads();
  }

  // ---- LSTM: 5 steps. Column-tile matvec: block owns 64 z-columns, waves
  // split the 1559 virtual rows, LDS reduce, ONE agent store per z-word.
  // ZERO atomics (prior rounds' 45-way atomicAdd serialized ~1400 RMW/line
  // at the coherent point ~ 20-30us/step — the real hidden cost).
  for (int step = 0; step < 5; ++step) {
    if (threadIdx.x < WC)
      sv[CD + threadIdx.x] = (step == 0) ? sxw[threadIdx.x]
                                         : rv[(step - 1) * WC + threadIdx.x];
    __syncthreads();
    float* zs = ws + OFF_Z + step * C4;
    if (blockIdx.x < ZJT) {
      int j0 = blockIdx.x * 64;
      int ncol = C4 - j0; if (ncol > 64) ncol = 64;
      float a0 = 0.f, a1 = 0.f, a2 = 0.f, a3 = 0.f;
      if (lane < ncol) {
        int r0 = wave * ZKCH, r1 = r0 + ZKCH; if (r1 > VROWS) r1 = VROWS;
        int rb = r1 < CD ? r1 : CD;           // rows from lr
        const float* p = lr + (size_t)r0 * C4 + (j0 + lane);
        int k = r0;
        for (; k + 4 <= rb; k += 4) {
          a0 = fmaf(sv[k],     p[0],                a0);
          a1 = fmaf(sv[k + 1], p[(size_t)C4],       a1);
          a2 = fmaf(sv[k + 2], p[2 * (size_t)C4],   a2);
          a3 = fmaf(sv[k + 3], p[3 * (size_t)C4],   a3);
          p += 4 * (size_t)C4;
        }
        for (; k < rb; ++k) { a0 = fmaf(sv[k], *p, a0); p += C4; }
        if (r1 > CD) {                         // rows from lk (xt part)
          int ka = r0 > CD ? r0 : CD;
          const float* q = lk + (size_t)(ka - CD) * C4 + (j0 + lane);
          for (k = ka; k + 4 <= r1; k += 4) {
            a0 = fmaf(sv[k],     q[0],              a0);
            a1 = fmaf(sv[k + 1], q[(size_t)C4],     a1);
            a2 = fmaf(sv[k + 2], q[2 * (size_t)C4], a2);
            a3 = fmaf(sv[k + 3], q[3 * (size_t)C4], a3);
            q += 4 * (size_t)C4;
          }
          for (; k < r1; ++k) { a0 = fmaf(sv[k], *q, a0); q += C4; }
        }
      }
      zred[threadIdx.x] = (a0 + a1) + (a2 + a3);
      __syncthreads();
      if (threadIdx.x < ncol) {
        float s = zred[threadIdx.x]       + zred[threadIdx.x + 64] +
                  zred[threadIdx.x + 128] + zred[threadIdx.x + 192] +
                  zred[threadIdx.x + 256] + zred[threadIdx.x + 320] +
                  zred[threadIdx.x + 384] + zred[threadIdx.x + 448];
        gstf(zs + j0 + threadIdx.x, s);
      }
    }
    ++ep; gbar(bars, rel, ep, gridDim.x);
    // gates: every block redundantly; z via agent loads; h/c stay in LDS
    for (int j = threadIdx.x; j < CD; j += 512) {
      float zi = gldf(zs + j)          + lb[j];
      float zf = gldf(zs + CD + j)     + lb[CD + j];
      float zg = gldf(zs + 2 * CD + j) + lb[2 * CD + j];
      float zo = gldf(zs + 3 * CD + j) + lb[3 * CD + j];
      float cn = sigm(zf) * scc[j] + sigm(zi) * tanhf(zg);
      scc[j] = cn;
      sv[j]  = sigm(zo) * tanhf(cn);
    }
    __syncthreads();
  }

  // ---- projection: column-tile, no atomics (19 blocks x 64 outputs) -------
  if (blockIdx.x < PJT) {
    int j0 = blockIdx.x * 64;
    int ncol = PROJ_J - j0; if (ncol > 64) ncol = 64;
    float a0 = 0.f, a1 = 0.f, a2 = 0.f, a3 = 0.f;
    if (lane < ncol) {
      int r0 = wave * PKCH, r1 = r0 + PKCH; if (r1 > CD) r1 = CD;
      const float* p; size_t st;
      if (j0 < OUTD) { p = Wo + (size_t)r0 * OUTD + (j0 + lane); st = OUTD; }  // 512%64==0: tile pure
      else { p = Wi + (size_t)r0 * IFACED + (j0 - OUTD + lane); st = IFACED; }
      int k = r0;
      for (; k + 4 <= r1; k += 4) {
        a0 = fmaf(sv[k],     p[0],      a0);
        a1 = fmaf(sv[k + 1], p[st],     a1);
        a2 = fmaf(sv[k + 2], p[2 * st], a2);
        a3 = fmaf(sv[k + 3], p[3 * st], a3);
        p += 4 * st;
      }
      for (; k < r1; ++k) { a0 = fmaf(sv[k], *p, a0); p += st; }
    }
    zred[threadIdx.x] = (a0 + a1) + (a2 + a3);
    __syncthreads();
    if (threadIdx.x < ncol) {
      float s = zred[threadIdx.x]       + zred[threadIdx.x + 64] +
                zred[threadIdx.x + 128] + zred[threadIdx.x + 192] +
                zred[threadIdx.x + 256] + zred[threadIdx.x + 320] +
                zred[threadIdx.x + 384] + zred[threadIdx.x + 448];
      int j = j0 + threadIdx.x;
      if (j < OUTD) gstf(po + j, s); else gstf(ifc + j - OUTD, s);
    }
  }
  ++ep; gbar(bars, rel, ep, gridDim.x);

  // ---- block 0 copies po -> out[0:512]; all blocks normalize keys ----------
  if (blockIdx.x == 0) out[threadIdx.x] = gldf(po + threadIdx.x);
  if (threadIdx.x < 320) {
    int w = threadIdx.x >> 6, ln = threadIdx.x & 63;
    float beta = 1.f + softplusf((w < 4) ? gldf(ifc + RR * WC + w)
                                         : gldf(ifc + RR * WC + RR + WC));
    const float* src = (w < 4) ? (ifc + w * WC) : (ifc + RR * WC + RR);
    float v0 = gldf(src + ln), v1 = gldf(src + ln + 64);
    float sq = v0 * v0 + v1 * v1;
    for (int off = 1; off < 64; off <<= 1) sq += __shfl_xor(sq, off);
    float rn = rsqrtf(fmaxf(sq, 1e-12f)) * beta;
    float* dstp = (w < 4) ? (s_rk + w * WC) : s_wk;
    dstp[ln] = v0 * rn; dstp[ln + 64] = v1 * rn;
  }
  __syncthreads();

  // ---- scores: blocks 1..; one row per thread; plain stores (same-thread
  // reload later -> L2 hit). Fused: alloc-col zero-fill + candidate filter.
  // Block 0 skips (frees it to run the alloc sort during the tail phase).
  const unsigned T2 = (gridDim.x - 1) * 512;
  if (blockIdx.x > 0) {
    float p0 = 0, p1 = 0, p2 = 0, p3 = 0, p4 = 0;
    const float4* K0 = (const float4*)(s_rk);
    const float4* K1 = (const float4*)(s_rk + WC);
    const float4* K2 = (const float4*)(s_rk + 2 * WC);
    const float4* K3 = (const float4*)(s_rk + 3 * WC);
    const float4* KW = (const float4*)(s_wk);
    for (unsigned i = (blockIdx.x - 1) * 512 + threadIdx.x; i < NN; i += T2) {
      const float4* rowp = (const float4*)(M + (size_t)i * WC);
      float a0 = 0, a1 = 0, a2 = 0, a3 = 0, a4 = 0, sq = 0;
      #pragma unroll 4
      for (int k = 0; k < 32; ++k) {
        float4 m = rowp[k];
        float4 c0v = K0[k], c1v = K1[k], c2v = K2[k], c3v = K3[k], cwv = KW[k];
        sq = fmaf(m.x, m.x, fmaf(m.y, m.y, fmaf(m.z, m.z, fmaf(m.w, m.w, sq))));
        a0 = fmaf(m.x, c0v.x, fmaf(m.y, c0v.y, fmaf(m.z, c0v.z, fmaf(m.w, c0v.w, a0))));
        a1 = fmaf(m.x, c1v.x, fmaf(m.y, c1v.y, fmaf(m.z, c1v.z, fmaf(m.w, c1v.w, a1))));
        a2 = fmaf(m.x, c2v.x, fmaf(m.y, c2v.y, fmaf(m.z, c2v.z, fmaf(m.w, c2v.w, a2))));
        a3 = fmaf(m.x, c3v.x, fmaf(m.y, c3v.y, fmaf(m.z, c3v.z, fmaf(m.w, c3v.w, a3))));
        a4 = fmaf(m.x, cwv.x, fmaf(m.y, cwv.y, fmaf(m.z, cwv.z, fmaf(m.w, cwv.w, a4))));
      }
      float rn = rsqrtf(fmaxf(sq, 1e-12f));
      float e0 = expf(a0 * rn), e1 = expf(a1 * rn), e2 = expf(a2 * rn),
            e3 = expf(a3 * rn), e4 = expf(a4 * rn);
      scores[0 * (size_t)NN + i] = e0;       // plain: same thread reloads
      scores[1 * (size_t)NN + i] = e1;
      scores[2 * (size_t)NN + i] = e2;
      scores[3 * (size_t)NN + i] = e3;
      scores[4 * (size_t)NN + i] = e4;
      gstf(out + OUTD + 5 * (size_t)NN + i, 0.f);  // alloc col: agent (block0 overwrites at L3)
      float u = us[i];
      if (u < 2e-3f) {
        unsigned slot = atomicAdd(ccnt, 1u);
        if (slot < CMAX)
          gstu64(cand + slot, ((unsigned long long)__float_as_uint(u) << 32) | i);
      }
      p0 += e0; p1 += e1; p2 += e2; p3 += e3; p4 += e4;
    }
    for (int off = 1; off < 64; off <<= 1) {
      p0 += __shfl_xor(p0, off); p1 += __shfl_xor(p1, off); p2 += __shfl_xor(p2, off);
      p3 += __shfl_xor(p3, off); p4 += __shfl_xor(p4, off);
    }
    if (lane == 0) { swred[wave][0] = p0; swred[wave][1] = p1; swred[wave][2] = p2;
                     swred[wave][3] = p3; swred[wave][4] = p4; }
    __syncthreads();
    if (threadIdx.x < 5) {
      float s = 0.f;
      for (int q = 0; q < 8; ++q) s += swred[q][threadIdx.x];
      gstf(bsum + blockIdx.x * 5 + threadIdx.x, s);
    }
  }
  ++ep; gbar(bars, rel, ep, gridDim.x);

  // ---- FINAL: block 0 -> alloc sort (concurrent); blocks 1.. -> normalize --
  if (blockIdx.x == 0) {
    // exact rank-sort of candidates + fp32 cumprod (reference order).
    // cumprod of sorted ascending uniforms underflows after ~10 terms; ranks
    // >=200 keep the zero written in the scores phase (ref there < 1e-38).
    int n = (int)gldu(ccnt); if (n > CMAX) n = CMAX;
    for (int t = threadIdx.x; t < n; t += 512) sc[t] = gldu64(cand + t);
    __syncthreads();
    for (int t = threadIdx.x; t < n; t += 512) {
      unsigned long long v = sc[t];
      int r = 0;
      for (int j2 = 0; j2 < n; ++j2) r += (sc[j2] < v);
      srt[r] = v;
    }
    __syncthreads();
    int lim = n < 200 ? n : 200;
    if (threadIdx.x == 0) {
      float cp = 1.f;
      for (int r = 0; r < lim; ++r) {
        cpe[r] = cp;
        cp *= __uint_as_float((unsigned)(srt[r] >> 32));
      }
    }
    __syncthreads();
    for (int r = threadIdx.x; r < lim; r += 512) {
      unsigned long long pr = srt[r];
      float s = __uint_as_float((unsigned)(pr >> 32));
      gstf(out + OUTD + 5 * (size_t)NN + (unsigned)pr, (1.f - s) * cpe[r]);
    }
  } else {
    // totals over bsum[1..511] (redundant per block)
    float q0 = 0, q1 = 0, q2 = 0, q3 = 0, q4 = 0;
    for (unsigned t = 1 + threadIdx.x; t < gridDim.x; t += 512) {
      const float* bp = bsum + t * 5;
      q0 += gldf(bp); q1 += gldf(bp + 1); q2 += gldf(bp + 2);
      q3 += gldf(bp + 3); q4 += gldf(bp + 4);
    }
    for (int off = 1; off < 64; off <<= 1) {
      q0 += __shfl_xor(q0, off); q1 += __shfl_xor(q1, off); q2 += __shfl_xor(q2, off);
      q3 += __shfl_xor(q3, off); q4 += __shfl_xor(q4, off);
    }
    if (lane == 0) { swred[wave][0] = q0; swred[wave][1] = q1; swred[wave][2] = q2;
                     swred[wave][3] = q3; swred[wave][4] = q4; }
    __syncthreads();
    if (threadIdx.x < 5) {
      float s = 0.f;
      for (int q = 0; q < 8; ++q) s += swred[q][threadIdx.x];
      ssum[threadIdx.x] = s;
    }
    __syncthreads();
    float i0 = 1.f / ssum[0], i1 = 1.f / ssum[1], i2 = 1.f / ssum[2],
          i3 = 1.f / ssum[3], i4 = 1.f / ssum[4];
    // SAME mapping as scores phase -> same thread reloads its own rows (L2 hit)
    for (unsigned i = (blockIdx.x - 1) * 512 + threadIdx.x; i < NN; i += T2) {
      float4 wr;
      wr.x = scores[0 * (size_t)NN + i] * i0;
      wr.y = scores[1 * (size_t)NN + i] * i1;
      wr.z = scores[2 * (size_t)NN + i] * i2;
      wr.w = scores[3 * (size_t)NN + i] * i3;
      *(float4*)(out + OUTD + (size_t)i * 4) = wr;   // single writer
      out[OUTD + 4 * (size_t)NN + i] = scores[4 * (size_t)NN + i] * i4;
    }
  }
}

extern "C" void kernel_launch(void* const* d_in, const int* in_sizes, int n_in,
                              void* d_out, int out_size, void* d_ws, size_t ws_size,
                              hipStream_t stream) {
  const float* x  = (const float*)d_in[0];
  const float* dk = (const float*)d_in[1];
  const float* db = (const float*)d_in[2];
  const float* lk = (const float*)d_in[3];
  const float* lr = (const float*)d_in[4];
  const float* lb = (const float*)d_in[5];
  const float* h0 = (const float*)d_in[6];
  const float* c0 = (const float*)d_in[7];
  const float* rv = (const float*)d_in[8];
  const float* Wo = (const float*)d_in[9];
  const float* Wi = (const float*)d_in[10];
  const float* M  = (const float*)d_in[11];
  const float* us = (const float*)d_in[12];
  float* out = (float*)d_out;
  float* ws  = (float*)d_ws;

  static int grid = 0;
  if (grid == 0) {
    int nb = 0;
    if (hipOccupancyMaxActiveBlocksPerMultiprocessor(&nb, (const void*)k_fused, 512, 0) != hipSuccess || nb < 1)
      nb = 1;
    long g = (long)nb * 256;        // 256 CUs
    grid = (int)(g < 512 ? g : 512);
  }

  // zero barrier stripes / release / ccnt only (z/po/ifc are stored, not
  // accumulated — no pre-zeroing needed anymore)
  k_init<<<1, 512, 0, stream>>>(ws);

  void* args[] = { &x, &dk, &db, &lk, &lr, &lb, &h0, &c0, &rv,
                   &Wo, &Wi, &M, &us, &out, &ws };
  hipLaunchCooperativeKernel((const void*)k_fused, dim3(grid), dim3(512),
                             args, 0, stream);
}

// Round 7
// 346.426 us; speedup vs baseline: 1.3608x; 1.3608x over previous
//
#include <hip/hip_runtime.h>
#include <math.h>

#define NN      262144
#define WC      128
#define RR      4
#define OUTD    512
#define IFACED  919
#define CD      1431
#define C4      5724
#define VROWS   1559   // CD + WC virtual rows ([h ; xt])
#define PROJ_J  1157   // 512 out + 645 used iface entries
#define CMAX    2048   // candidate cap (E[n]=524 @ thr 2e-3)

// zmv 2D grid: 90 col-tiles(64) x 5 row-chunks(312) = 450 blocks (all CUs busy)
#define ZCT     90
#define ZKC     5
#define ZROWS   312    // 8 waves x 39 rows
#define ZGRID   450
// proj 2D grid: 19 col-tiles(64) x 8 row-chunks(179) = 152 blocks
#define PCT     19
#define PKC     8
#define PROWS   179    // 8 waves x 23 rows (clamped)
#define PGRID   152

// ---- ws word offsets (everything fully re-written each iteration; no init)
#define OFF_CA      0        // f32[1431] c ping
#define OFF_CB      1536     // f32[1431] c pong
#define OFF_ZP      3072     // f32[5 steps][5 kc][C4] = 143100
#define OFF_PP      146176   // f32[8][PROJ_J] = 9256
#define OFF_BSUM    155456   // f32[512*5]
#define OFF_CCNT    158016   // u32 (own line)
#define OFF_CAND    158080   // u64[2048] (even word -> 8B aligned)
#define OFF_SCORES  162176   // f32[5*NN]

__device__ __forceinline__ float sigm(float x) { return 1.f / (1.f + expf(-x)); }
__device__ __forceinline__ float softplusf(float x) { return x > 20.f ? x : log1pf(expf(x)); }

// ---- gates for rows [r0, r1c): z = lb + sum of 5 zpart chunks; h -> sv -----
__device__ __forceinline__ void do_gates_part(const float* __restrict__ zp,
    const float* __restrict__ lb, const float* __restrict__ cprev,
    float* __restrict__ cnext, float* sv, int r0, int r1c, bool writeC) {
  for (int j = r0 + (int)threadIdx.x; j < r1c; j += 512) {
    float zi = lb[j], zf = lb[CD + j], zg = lb[2 * CD + j], zo = lb[3 * CD + j];
    #pragma unroll
    for (int kc = 0; kc < ZKC; ++kc) {
      const float* zz = zp + (size_t)kc * C4;
      zi += zz[j]; zf += zz[CD + j]; zg += zz[2 * CD + j]; zo += zz[3 * CD + j];
    }
    float cn = sigm(zf) * cprev[j] + sigm(zi) * tanhf(zg);
    if (writeC) cnext[j] = cn;
    sv[j] = sigm(zo) * tanhf(cn);
  }
  __syncthreads();
}

// ---- zmv partial: block (ct,kc) computes rows[kc] x cols[ct] -> zpart ------
__device__ __forceinline__ void do_zmv(const float* __restrict__ lr,
    const float* __restrict__ lk, const float* sv, float* __restrict__ zout,
    float* zred) {
  const int wave = threadIdx.x >> 6, lane = threadIdx.x & 63;
  const int ct = blockIdx.x % ZCT, kc = blockIdx.x / ZCT;
  const int j0 = ct * 64;
  int ncol = C4 - j0; if (ncol > 64) ncol = 64;
  int r0 = kc * ZROWS, r1 = r0 + ZROWS; if (r1 > VROWS) r1 = VROWS;
  int rw0 = r0 + wave * 39, rw1 = rw0 + 39; if (rw1 > r1) rw1 = r1;
  float a0 = 0, a1 = 0, a2 = 0, a3 = 0;
  if (lane < ncol && rw0 < rw1) {
    int rb = rw1 < CD ? rw1 : CD;
    int k = rw0;
    if (k < rb) {
      const float* p = lr + (size_t)k * C4 + (j0 + lane);
      for (; k + 4 <= rb; k += 4) {
        a0 = fmaf(sv[k],     p[0],              a0);
        a1 = fmaf(sv[k + 1], p[(size_t)C4],     a1);
        a2 = fmaf(sv[k + 2], p[2 * (size_t)C4], a2);
        a3 = fmaf(sv[k + 3], p[3 * (size_t)C4], a3);
        p += 4 * (size_t)C4;
      }
      for (; k < rb; ++k) { a0 = fmaf(sv[k], *p, a0); p += C4; }
    }
    if (rw1 > CD) {
      int ka = rw0 > CD ? rw0 : CD;
      const float* q = lk + (size_t)(ka - CD) * C4 + (j0 + lane);
      for (k = ka; k + 4 <= rw1; k += 4) {
        a0 = fmaf(sv[k],     q[0],              a0);
        a1 = fmaf(sv[k + 1], q[(size_t)C4],     a1);
        a2 = fmaf(sv[k + 2], q[2 * (size_t)C4], a2);
        a3 = fmaf(sv[k + 3], q[3 * (size_t)C4], a3);
        q += 4 * (size_t)C4;
      }
      for (; k < rw1; ++k) { a0 = fmaf(sv[k], *q, a0); q += C4; }
    }
  }
  zred[threadIdx.x] = (a0 + a1) + (a2 + a3);
  __syncthreads();
  if ((int)threadIdx.x < ncol) {
    float s = zred[threadIdx.x]       + zred[threadIdx.x + 64] +
              zred[threadIdx.x + 128] + zred[threadIdx.x + 192] +
              zred[threadIdx.x + 256] + zred[threadIdx.x + 320] +
              zred[threadIdx.x + 384] + zred[threadIdx.x + 448];
    zout[(size_t)kc * C4 + j0 + threadIdx.x] = s;
  }
}

// ---- k1: z1 partials from [h0 ; xw] ---------------------------------------
__global__ __launch_bounds__(512) void k_z1(const float* __restrict__ x,
    const float* __restrict__ dk, const float* __restrict__ db,
    const float* __restrict__ lk, const float* __restrict__ lr,
    const float* __restrict__ h0, float* __restrict__ ws) {
  __shared__ float sv[VROWS];
  __shared__ float sxw[512];
  __shared__ float zred[512];
  for (int t = threadIdx.x; t < CD; t += 512) sv[t] = h0[t];
  {
    int j = threadIdx.x & (WC - 1), kcw = threadIdx.x >> 7;
    const float* col = dk + j;
    float a = 0.f;
    int k0 = kcw * 128;
    #pragma unroll 8
    for (int k = k0; k < k0 + 128; ++k) a = fmaf(x[k], col[(size_t)k * WC], a);
    sxw[threadIdx.x] = a;
  }
  __syncthreads();
  if (threadIdx.x < WC)
    sv[CD + threadIdx.x] = db[threadIdx.x] + sxw[threadIdx.x] +
        sxw[threadIdx.x + 128] + sxw[threadIdx.x + 256] + sxw[threadIdx.x + 384];
  __syncthreads();
  do_zmv(lr, lk, sv, ws + OFF_ZP, zred);
}

// ---- k2..k5: gates(t) on own row-chunk + zmv(t+1) -------------------------
__global__ __launch_bounds__(512) void k_mid(const float* __restrict__ lk,
    const float* __restrict__ lr, const float* __restrict__ lb,
    const float* __restrict__ zp_in, const float* __restrict__ cprev,
    float* __restrict__ cnext, const float* __restrict__ xt,
    float* __restrict__ zp_out) {
  __shared__ float sv[VROWS];
  __shared__ float zred[512];
  const int ct = blockIdx.x % ZCT, kc = blockIdx.x / ZCT;
  int r0 = kc * ZROWS, r1 = r0 + ZROWS; if (r1 > VROWS) r1 = VROWS;
  int r1c = r1 < CD ? r1 : CD;
  // ct==0 block of each kc writes c for its (disjoint) row range
  do_gates_part(zp_in, lb, cprev, cnext, sv, r0, r1c, ct == 0);
  if (threadIdx.x < WC) sv[CD + threadIdx.x] = xt[threadIdx.x];
  __syncthreads();
  do_zmv(lr, lk, sv, zp_out, zred);
}

// ---- k6: gates(5) on own row-chunk + proj partials ------------------------
__global__ __launch_bounds__(512) void k_last(const float* __restrict__ lb,
    const float* __restrict__ zp_in, const float* __restrict__ cprev,
    const float* __restrict__ Wo, const float* __restrict__ Wi,
    float* __restrict__ ws) {
  __shared__ float sv[VROWS];
  __shared__ float zred[512];
  const int wave = threadIdx.x >> 6, lane = threadIdx.x & 63;
  const int ct = blockIdx.x % PCT, kc = blockIdx.x / PCT;
  int r0 = kc * PROWS, r1 = r0 + PROWS; if (r1 > CD) r1 = CD;
  do_gates_part(zp_in, lb, cprev, nullptr, sv, r0, r1, false);
  if (blockIdx.x == 0 && threadIdx.x == 0) *(unsigned*)(ws + OFF_CCNT) = 0u;
  const int j0 = ct * 64;
  int ncol = PROJ_J - j0; if (ncol > 64) ncol = 64;
  int rw0 = r0 + wave * 23, rw1 = rw0 + 23; if (rw1 > r1) rw1 = r1;
  float a0 = 0, a1 = 0, a2 = 0, a3 = 0;
  if (lane < ncol && rw0 < rw1) {
    const float* p; size_t st;
    if (j0 < OUTD) { p = Wo + (size_t)rw0 * OUTD + (j0 + lane); st = OUTD; }
    else { p = Wi + (size_t)rw0 * IFACED + (j0 - OUTD + lane); st = IFACED; }
    int k = rw0;
    for (; k + 4 <= rw1; k += 4) {
      a0 = fmaf(sv[k],     p[0],      a0);
      a1 = fmaf(sv[k + 1], p[st],     a1);
      a2 = fmaf(sv[k + 2], p[2 * st], a2);
      a3 = fmaf(sv[k + 3], p[3 * st], a3);
      p += 4 * st;
    }
    for (; k < rw1; ++k) { a0 = fmaf(sv[k], *p, a0); p += st; }
  }
  zred[threadIdx.x] = (a0 + a1) + (a2 + a3);
  __syncthreads();
  if ((int)threadIdx.x < ncol) {
    float s = zred[threadIdx.x]       + zred[threadIdx.x + 64] +
              zred[threadIdx.x + 128] + zred[threadIdx.x + 192] +
              zred[threadIdx.x + 256] + zred[threadIdx.x + 320] +
              zred[threadIdx.x + 384] + zred[threadIdx.x + 448];
    ws[OFF_PP + (size_t)kc * PROJ_J + j0 + threadIdx.x] = s;
  }
}

// ---- k7: reduce ppart -> keys (redundant) ; scores 1 row/thread -----------
__global__ __launch_bounds__(512) void k_scores(const float* __restrict__ M,
    const float* __restrict__ us, float* __restrict__ out, float* __restrict__ ws) {
  __shared__ float sifc[IFACED];
  __shared__ float s_rk[RR * WC];
  __shared__ float s_wk[WC];
  __shared__ float swred[8][5];
  const float* pp = ws + OFF_PP;
  for (int c = threadIdx.x; c < IFACED; c += 512) {
    float s = 0.f;
    #pragma unroll
    for (int kc = 0; kc < PKC; ++kc) s += pp[(size_t)kc * PROJ_J + OUTD + c];
    sifc[c] = s;
  }
  if (blockIdx.x == 0) {           // out-proj final reduce
    float s = 0.f;
    #pragma unroll
    for (int kc = 0; kc < PKC; ++kc) s += pp[(size_t)kc * PROJ_J + threadIdx.x];
    out[threadIdx.x] = s;
  }
  __syncthreads();
  if (threadIdx.x < 320) {
    int w = threadIdx.x >> 6, ln = threadIdx.x & 63;
    float beta = 1.f + softplusf((w < 4) ? sifc[RR * WC + w] : sifc[RR * WC + RR + WC]);
    const float* src = (w < 4) ? (sifc + w * WC) : (sifc + RR * WC + RR);
    float v0 = src[ln], v1 = src[ln + 64];
    float sq = v0 * v0 + v1 * v1;
    for (int off = 1; off < 64; off <<= 1) sq += __shfl_xor(sq, off);
    float rn = rsqrtf(fmaxf(sq, 1e-12f)) * beta;
    float* dstp = (w < 4) ? (s_rk + w * WC) : s_wk;
    dstp[ln] = v0 * rn; dstp[ln + 64] = v1 * rn;
  }
  __syncthreads();

  float* scores = ws + OFF_SCORES;
  unsigned* ccnt = (unsigned*)(ws + OFF_CCNT);
  unsigned long long* cand = (unsigned long long*)(ws + OFF_CAND);
  unsigned i = blockIdx.x * 512 + threadIdx.x;   // 512x512 == NN exactly
  const float4* rowp = (const float4*)(M + (size_t)i * WC);
  const float4* K0 = (const float4*)(s_rk);
  const float4* K1 = (const float4*)(s_rk + WC);
  const float4* K2 = (const float4*)(s_rk + 2 * WC);
  const float4* K3 = (const float4*)(s_rk + 3 * WC);
  const float4* KW = (const float4*)(s_wk);
  float a0 = 0, a1 = 0, a2 = 0, a3 = 0, a4 = 0, sq = 0;
  #pragma unroll 4
  for (int k = 0; k < 32; ++k) {
    float4 m = rowp[k];
    float4 c0v = K0[k], c1v = K1[k], c2v = K2[k], c3v = K3[k], cwv = KW[k];
    sq = fmaf(m.x, m.x, fmaf(m.y, m.y, fmaf(m.z, m.z, fmaf(m.w, m.w, sq))));
    a0 = fmaf(m.x, c0v.x, fmaf(m.y, c0v.y, fmaf(m.z, c0v.z, fmaf(m.w, c0v.w, a0))));
    a1 = fmaf(m.x, c1v.x, fmaf(m.y, c1v.y, fmaf(m.z, c1v.z, fmaf(m.w, c1v.w, a1))));
    a2 = fmaf(m.x, c2v.x, fmaf(m.y, c2v.y, fmaf(m.z, c2v.z, fmaf(m.w, c2v.w, a2))));
    a3 = fmaf(m.x, c3v.x, fmaf(m.y, c3v.y, fmaf(m.z, c3v.z, fmaf(m.w, c3v.w, a3))));
    a4 = fmaf(m.x, cwv.x, fmaf(m.y, cwv.y, fmaf(m.z, cwv.z, fmaf(m.w, cwv.w, a4))));
  }
  float rn = rsqrtf(fmaxf(sq, 1e-12f));
  float e0 = expf(a0 * rn), e1 = expf(a1 * rn), e2 = expf(a2 * rn),
        e3 = expf(a3 * rn), e4 = expf(a4 * rn);
  scores[0 * (size_t)NN + i] = e0;
  scores[1 * (size_t)NN + i] = e1;
  scores[2 * (size_t)NN + i] = e2;
  scores[3 * (size_t)NN + i] = e3;
  scores[4 * (size_t)NN + i] = e4;
  out[OUTD + 5 * (size_t)NN + i] = 0.f;          // alloc col zero-fill
  float u = us[i];
  if (u < 2e-3f) {
    unsigned slot = atomicAdd(ccnt, 1u);
    if (slot < CMAX)
      cand[slot] = ((unsigned long long)__float_as_uint(u) << 32) | i;
  }
  float p0 = e0, p1 = e1, p2 = e2, p3 = e3, p4 = e4;
  for (int off = 1; off < 64; off <<= 1) {
    p0 += __shfl_xor(p0, off); p1 += __shfl_xor(p1, off); p2 += __shfl_xor(p2, off);
    p3 += __shfl_xor(p3, off); p4 += __shfl_xor(p4, off);
  }
  int wave = threadIdx.x >> 6, ln = threadIdx.x & 63;
  if (ln == 0) { swred[wave][0] = p0; swred[wave][1] = p1; swred[wave][2] = p2;
                 swred[wave][3] = p3; swred[wave][4] = p4; }
  __syncthreads();
  if (threadIdx.x < 5) {
    float s = 0.f;
    for (int q = 0; q < 8; ++q) s += swred[q][threadIdx.x];
    ws[OFF_BSUM + blockIdx.x * 5 + threadIdx.x] = s;
  }
}

// ---- k8: block 0 alloc ; blocks 1..511 normalize --------------------------
__global__ __launch_bounds__(512) void k_tail(float* __restrict__ out,
    float* __restrict__ ws) {
  __shared__ float swred[8][5];
  __shared__ float ssum[5];
  __shared__ unsigned long long sc[CMAX];
  __shared__ unsigned long long srt[CMAX];
  __shared__ float cpe[200];
  const float* scores = ws + OFF_SCORES;
  if (blockIdx.x == 0) {
    // exact rank-sort of candidates + fp32 cumprod (reference order).
    // cumprod of sorted ascending uniforms underflows after ~10 terms; ranks
    // >=200 keep the zero written by k_scores (ref values there < 1e-38).
    int n = (int)*(const unsigned*)(ws + OFF_CCNT); if (n > CMAX) n = CMAX;
    const unsigned long long* cand = (const unsigned long long*)(ws + OFF_CAND);
    for (int t = threadIdx.x; t < n; t += 512) sc[t] = cand[t];
    __syncthreads();
    for (int t = threadIdx.x; t < n; t += 512) {
      unsigned long long v = sc[t];
      int r = 0;
      for (int j2 = 0; j2 < n; ++j2) r += (sc[j2] < v);
      srt[r] = v;
    }
    __syncthreads();
    int lim = n < 200 ? n : 200;
    if (threadIdx.x == 0) {
      float cp = 1.f;
      for (int r = 0; r < lim; ++r) {
        cpe[r] = cp;
        cp *= __uint_as_float((unsigned)(srt[r] >> 32));
      }
    }
    __syncthreads();
    for (int r = threadIdx.x; r < lim; r += 512) {
      unsigned long long pr = srt[r];
      float s = __uint_as_float((unsigned)(pr >> 32));
      out[OUTD + 5 * (size_t)NN + (unsigned)pr] = (1.f - s) * cpe[r];
    }
  } else {
    const float* bsum = ws + OFF_BSUM;
    float q0 = 0, q1 = 0, q2 = 0, q3 = 0, q4 = 0;
    {
      const float* bp = bsum + threadIdx.x * 5;   // 512 entries, 1 per thread
      q0 = bp[0]; q1 = bp[1]; q2 = bp[2]; q3 = bp[3]; q4 = bp[4];
    }
    for (int off = 1; off < 64; off <<= 1) {
      q0 += __shfl_xor(q0, off); q1 += __shfl_xor(q1, off); q2 += __shfl_xor(q2, off);
      q3 += __shfl_xor(q3, off); q4 += __shfl_xor(q4, off);
    }
    int wave = threadIdx.x >> 6, ln = threadIdx.x & 63;
    if (ln == 0) { swred[wave][0] = q0; swred[wave][1] = q1; swred[wave][2] = q2;
                   swred[wave][3] = q3; swred[wave][4] = q4; }
    __syncthreads();
    if (threadIdx.x < 5) {
      float s = 0.f;
      for (int q = 0; q < 8; ++q) s += swred[q][threadIdx.x];
      ssum[threadIdx.x] = s;
    }
    __syncthreads();
    float i0 = 1.f / ssum[0], i1 = 1.f / ssum[1], i2 = 1.f / ssum[2],
          i3 = 1.f / ssum[3], i4 = 1.f / ssum[4];
    unsigned stride = 511u * 512u;
    for (unsigned i = (blockIdx.x - 1) * 512 + threadIdx.x; i < NN; i += stride) {
      float4 wr;
      wr.x = scores[0 * (size_t)NN + i] * i0;
      wr.y = scores[1 * (size_t)NN + i] * i1;
      wr.z = scores[2 * (size_t)NN + i] * i2;
      wr.w = scores[3 * (size_t)NN + i] * i3;
      *(float4*)(out + OUTD + (size_t)i * 4) = wr;
      out[OUTD + 4 * (size_t)NN + i] = scores[4 * (size_t)NN + i] * i4;
    }
  }
}

extern "C" void kernel_launch(void* const* d_in, const int* in_sizes, int n_in,
                              void* d_out, int out_size, void* d_ws, size_t ws_size,
                              hipStream_t stream) {
  const float* x  = (const float*)d_in[0];
  const float* dk = (const float*)d_in[1];
  const float* db = (const float*)d_in[2];
  const float* lk = (const float*)d_in[3];
  const float* lr = (const float*)d_in[4];
  const float* lb = (const float*)d_in[5];
  const float* h0 = (const float*)d_in[6];
  const float* c0 = (const float*)d_in[7];
  const float* rv = (const float*)d_in[8];
  const float* Wo = (const float*)d_in[9];
  const float* Wi = (const float*)d_in[10];
  const float* M  = (const float*)d_in[11];
  const float* us = (const float*)d_in[12];
  float* out = (float*)d_out;
  float* ws  = (float*)d_ws;

  float* cA = ws + OFF_CA;
  float* cB = ws + OFF_CB;
  #define ZB(s) (ws + OFF_ZP + (size_t)((s) - 1) * ZKC * C4)

  k_z1<<<ZGRID, 512, 0, stream>>>(x, dk, db, lk, lr, h0, ws);
  k_mid<<<ZGRID, 512, 0, stream>>>(lk, lr, lb, ZB(1), c0, cA, rv + 0 * WC, ZB(2));
  k_mid<<<ZGRID, 512, 0, stream>>>(lk, lr, lb, ZB(2), cA, cB, rv + 1 * WC, ZB(3));
  k_mid<<<ZGRID, 512, 0, stream>>>(lk, lr, lb, ZB(3), cB, cA, rv + 2 * WC, ZB(4));
  k_mid<<<ZGRID, 512, 0, stream>>>(lk, lr, lb, ZB(4), cA, cB, rv + 3 * WC, ZB(5));
  k_last<<<PGRID, 512, 0, stream>>>(lb, ZB(5), cB, Wo, Wi, ws);
  k_scores<<<512, 512, 0, stream>>>(M, us, out, ws);
  k_tail<<<512, 512, 0, stream>>>(out, ws);
}